// Round 9
// baseline (252.626 us; speedup 1.0000x reference)
//
#include <hip/hip_runtime.h>

#define DD 128
#define HH 512
#define WW 512
#define NVOX (DD*HH*WW)          // 33554432
#define THRESHV 0.997f
#define KPEAKS 131072
#define PEAK_CAP (1u<<18)        // 262144 peak slots (expect ~63K)
#define NBINS 65536

// peaks all lie in (0.997, 1.0): float bits have constant upper 16 bits
// 0x3F7F -> low 16 bits monotone in value. bin=(~bits)&0xFFFF so ascending
// bin == descending value. Exact-value ties are COMMON -> tie-fix required.

// ---------------- K0: init scratch (ws is poisoned 0xAA before every call).
__global__ void k_init(unsigned* counters, unsigned* hist) {
    unsigned t = blockIdx.x * 1024u + threadIdx.x;
    if (t < 64) counters[t] = 0u;
    if (t < NBINS) hist[t] = 0u;
}

// ---------------- K1: stream + verify + centroid, TWO slabs per block.
// R17: R0's proven body, x2 slabs with the s1 DMA issued BEFORE verify(s0).
// Evidence chain: R15 probe -> scan convoy 50us + verify 34us with ZERO
// overlap (50+34=84 exactly; lockstep blocks). R16 -> verify locality dies
// when concurrent slab footprint exceeds the 4MB/XCD L2 (FETCH 92->186MB).
// So: keep R0's 8192-voxel slab + same-XCD z-neighbor mapping, and create
// the missing overlap INSIDE the block: verify(s0)'s global gathers run
// while slab1's global_load_lds flight is outstanding; the next
// __syncthreads' implicit vmcnt(0) drain is exactly the wait for s1.
// Plain __syncthreads everywhere (no raw-barrier/counted-vmcnt risk class).
// LDS: 64KB tiles + ~7KB aux -> 2 blocks/CU; footprint 32CUx2x64KB = 4MB ✓.
__global__ __launch_bounds__(512, 4)
void k_find(const float4* __restrict__ vol4, const float* __restrict__ vol,
            unsigned* counters, unsigned* hist,
            unsigned long long* keys, float4* psums) {
    __shared__ float4 tile[2][2048];          // 2 x 32KB slab buffers
    __shared__ unsigned lcnt, pcnt, lbase;
    __shared__ unsigned cidx[384];            // per-slab candidates (E~25)
    __shared__ unsigned long long lbuf[192];  // survivors, both slabs (E~32)
    __shared__ float4 sbuf[192];
    if (threadIdx.x == 0) { lcnt = 0; pcnt = 0; }
    __syncthreads();

    unsigned t = threadIdx.x;
    unsigned lane = t & 63u;
    unsigned w = t >> 6;                      // wave id 0..7 (wave-uniform)
    unsigned blockBase4 = blockIdx.x * 4096u; // float4 units; 16384 voxels
    int dz = (int)lane / 7, dy = (int)lane - dz * 7;   // meaningful for lane<49

    // issue one slab's DMA (4 x 16B per thread, wave-uniform LDS slots)
    auto dma = [&](unsigned s) {
#pragma unroll
        for (unsigned i = 0; i < 4; i++) {
            unsigned f = i * 512u + w * 64u;
            const float4* gp = vol4 + blockBase4 + s * 2048u + f + lane;
            __builtin_amdgcn_global_load_lds(
                (const __attribute__((address_space(1))) unsigned int*)gp,
                (__attribute__((address_space(3))) unsigned int*)(&tile[s][f]),
                16, 0, 0);
        }
    };

    // threshold-scan slab s from its LDS tile into cidx/lcnt
    auto scan = [&](unsigned s) {
        unsigned m = 0u;
        float4 v[4];
#pragma unroll
        for (unsigned i = 0; i < 4; i++) v[i] = tile[s][i * 512u + t];
#pragma unroll
        for (unsigned i = 0; i < 4; i++) {
            m |= (v[i].x > THRESHV ? 1u : 0u) << (4 * i);
            m |= (v[i].y > THRESHV ? 1u : 0u) << (4 * i + 1);
            m |= (v[i].z > THRESHV ? 1u : 0u) << (4 * i + 2);
            m |= (v[i].w > THRESHV ? 1u : 0u) << (4 * i + 3);
        }
        unsigned sbase4 = blockBase4 + s * 2048u;
        while (m) {
            int b = __ffs(m) - 1;
            m &= m - 1u;
            unsigned f4 = sbase4 + (unsigned)(b >> 2) * 512u + t;
            cidx[atomicAdd(&lcnt, 1u) & 383u] = f4 * 4u + (unsigned)(b & 3);
        }
    };

    // verify candidates [0,n) -- R0 body verbatim (2 candidates/wave-iter)
    auto verify = [&](unsigned n) {
        for (unsigned base = w * 2u; base < n; base += 16u) {
            bool has2 = (base + 1u < n);
            unsigned idxA = cidx[base];
            unsigned idxB = has2 ? cidx[base + 1u] : idxA;
            int zA = idxA >> 18, yA = (idxA >> 9) & 511, xA = idxA & 511;
            int zB = idxB >> 18, yB = (idxB >> 9) & 511, xB = idxB & 511;
            int nzA = zA + dz - 3, nyA = yA + dy - 3;
            int nzB = zB + dz - 3, nyB = yB + dy - 3;
            bool rowokA = (lane < 49) && ((unsigned)nzA < DD) && ((unsigned)nyA < HH);
            bool rowokB = (lane < 49) && ((unsigned)nzB < DD) && ((unsigned)nyB < HH);
            size_t rbA = rowokA ? (((size_t)(unsigned)nzA << 18) | ((size_t)(unsigned)nyA << 9))
                                : (((size_t)zA << 18) | ((size_t)yA << 9));
            size_t rbB = rowokB ? (((size_t)(unsigned)nzB << 18) | ((size_t)(unsigned)nyB << 9))
                                : (((size_t)zB << 18) | ((size_t)yB << 9));
            float rvA[7], rvB[7];
            bool intAB = (xA >= 3) && (xA <= WW - 4) && (xB >= 3) && (xB <= WW - 4);
            if (intAB) {
                float4 fA0 = *(const float4*)(vol + rbA + (unsigned)(xA - 3));
                float4 fA1 = *(const float4*)(vol + rbA + (unsigned)(xA + 1));
                float4 fB0 = *(const float4*)(vol + rbB + (unsigned)(xB - 3));
                float4 fB1 = *(const float4*)(vol + rbB + (unsigned)(xB + 1));
                rvA[0] = fA0.x; rvA[1] = fA0.y; rvA[2] = fA0.z; rvA[3] = fA0.w;
                rvA[4] = fA1.x; rvA[5] = fA1.y; rvA[6] = fA1.z;
                rvB[0] = fB0.x; rvB[1] = fB0.y; rvB[2] = fB0.z; rvB[3] = fB0.w;
                rvB[4] = fB1.x; rvB[5] = fB1.y; rvB[6] = fB1.z;
            } else {
                // rare x-edge path (wave-uniform): clamped scalar loads
#pragma unroll
                for (int d = 0; d < 7; d++) {
                    int nxA = xA + d - 3;
                    bool okA = (unsigned)nxA < WW;
                    float va = vol[rbA + (unsigned)(okA ? nxA : xA)];
                    rvA[d] = okA ? va : 0.f;
                    int nxB = xB + d - 3;
                    bool okB = (unsigned)nxB < WW;
                    float vb = vol[rbB + (unsigned)(okB ? nxB : xB)];
                    rvB[d] = okB ? vb : 0.f;
                }
            }
            if (!rowokA) {
#pragma unroll
                for (int d = 0; d < 7; d++) rvA[d] = 0.f;
            }
            if (!rowokB) {
#pragma unroll
                for (int d = 0; d < 7; d++) rvB[d] = 0.f;
            }
            float centerA = __shfl(rvA[3], 24);
            float centerB = __shfl(rvB[3], 24);

            // ---- candidate A
            {
                bool kill = false;
                float s0r = 0.f, sxr = 0.f;
#pragma unroll
                for (int d = 0; d < 7; d++) {
                    kill |= rvA[d] > centerA;
                    s0r += rvA[d];
                    sxr += rvA[d] * (float)(d - 3);
                }
                if (!__any(kill)) {
                    float s0 = s0r, sx = sxr;
                    float sy = s0r * (float)(dy - 3);
                    float sz = s0r * (float)(dz - 3);
                    for (int off = 32; off; off >>= 1) {
                        s0 += __shfl_down(s0, off);
                        sx += __shfl_down(sx, off);
                        sy += __shfl_down(sy, off);
                        sz += __shfl_down(sz, off);
                    }
                    if (lane == 0) {
                        unsigned bits = __float_as_uint(centerA);
                        atomicAdd(&hist[(~bits) & 0xFFFFu], 1u);
                        unsigned li = atomicAdd(&pcnt, 1u);
                        if (li < 192u) {
                            lbuf[li] = ((unsigned long long)bits << 32) | idxA;
                            sbuf[li] = make_float4(s0, sx, sy, sz);
                        }
                    }
                }
            }
            // ---- candidate B
            if (has2) {
                bool kill = false;
                float s0r = 0.f, sxr = 0.f;
#pragma unroll
                for (int d = 0; d < 7; d++) {
                    kill |= rvB[d] > centerB;
                    s0r += rvB[d];
                    sxr += rvB[d] * (float)(d - 3);
                }
                if (!__any(kill)) {
                    float s0 = s0r, sx = sxr;
                    float sy = s0r * (float)(dy - 3);
                    float sz = s0r * (float)(dz - 3);
                    for (int off = 32; off; off >>= 1) {
                        s0 += __shfl_down(s0, off);
                        sx += __shfl_down(sx, off);
                        sy += __shfl_down(sy, off);
                        sz += __shfl_down(sz, off);
                    }
                    if (lane == 0) {
                        unsigned bits = __float_as_uint(centerB);
                        atomicAdd(&hist[(~bits) & 0xFFFFu], 1u);
                        unsigned li = atomicAdd(&pcnt, 1u);
                        if (li < 192u) {
                            lbuf[li] = ((unsigned long long)bits << 32) | idxB;
                            sbuf[li] = make_float4(s0, sx, sy, sz);
                        }
                    }
                }
            }
        }
    };

    // ---- slab 0: DMA, drain, scan
    dma(0u);
    __builtin_amdgcn_s_waitcnt(0);
    __syncthreads();
    scan(0u);
    __syncthreads();                          // lcnt/cidx(s0) final
    unsigned n0 = lcnt > 384u ? 384u : lcnt;

    // ---- issue slab1 DMA, then verify slab0 while it flies
    dma(1u);
    verify(n0);
    __syncthreads();                          // implicit vmcnt(0): s1 landed;
    if (t == 0) lcnt = 0;                     // and cidx reads complete
    __syncthreads();

    // ---- slab 1: scan + verify
    scan(1u);
    __syncthreads();
    unsigned n1 = lcnt > 384u ? 384u : lcnt;
    verify(n1);

    // ---- flush survivors (both slabs)
    __syncthreads();
    if (threadIdx.x == 0) lbase = atomicAdd(&counters[1], pcnt);
    __syncthreads();
    unsigned np = pcnt > 192u ? 192u : pcnt;
    for (unsigned i = threadIdx.x; i < np; i += 512u) {
        unsigned p = lbase + i;
        if (p < PEAK_CAP) { keys[p] = lbuf[i]; psums[p] = sbuf[i]; }
    }
}

// ---------------- K2: parallel scan, stage 1. 256 blocks x 256 thr.
// Each block scans its 256-bin chunk; cursor gets the block-LOCAL exclusive
// prefix; blocksum gets the chunk total. Stage 2 is fused into k_scatter.
__global__ void k_scan_a(const unsigned* __restrict__ hist,
                         unsigned* __restrict__ cursor,
                         unsigned* __restrict__ blocksum) {
    __shared__ unsigned sc[256];
    unsigned t = threadIdx.x, b = blockIdx.x;
    unsigned h = hist[b * 256u + t];
    sc[t] = h;
    __syncthreads();
    for (unsigned off = 1u; off < 256u; off <<= 1) {
        unsigned v = (t >= off) ? sc[t - off] : 0u;
        __syncthreads();
        sc[t] += v;
        __syncthreads();
    }
    cursor[b * 256u + t] = sc[t] - h;         // block-local exclusive
    if (t == 255u) blocksum[b] = sc[255];
}

// ---------------- K3: scatter (with scan stage-2 fused). Each block first
// scans the 256 chunk totals in LDS (1KB, L2-hot), then final position =
// chunk_base[bin>>8] + atomicAdd(cursor[bin]) where cursor holds the
// block-local prefix -- algebraically identical to the old scan_b+scatter.
__global__ void k_scatter(const unsigned* __restrict__ counters,
                          const unsigned long long* __restrict__ keys,
                          const unsigned* __restrict__ blocksum,
                          unsigned* cursor, unsigned long long* sorted,
                          unsigned* sslot,
                          float4* __restrict__ out, float* __restrict__ valid) {
    __shared__ unsigned bs[256];
    unsigned t = threadIdx.x;
    if (t < 256u) bs[t] = blocksum[t];
    __syncthreads();
    for (unsigned off = 1u; off < 256u; off <<= 1) {
        unsigned v = (t < 256u && t >= off) ? bs[t - off] : 0u;
        __syncthreads();
        if (t < 256u) bs[t] += v;
        __syncthreads();
    }
    unsigned np = counters[1]; if (np > PEAK_CAP) np = PEAK_CAP;
    unsigned g = blockIdx.x * 1024u + t;
    if (g < np) {
        unsigned long long key = keys[g];
        unsigned bits = (unsigned)(key >> 32);
        unsigned bin = (~bits) & 0xFFFFu;
        unsigned c = bin >> 8;
        unsigned base_c = (c > 0u) ? bs[c - 1u] : 0u;
        unsigned pos = base_c + atomicAdd(&cursor[bin], 1u);
        if (pos < PEAK_CAP) { sorted[pos] = key; sslot[pos] = g; }
    } else if (g < KPEAKS) {
        out[g] = make_float4(0.f, 0.f, 0.f, 0.f);
        valid[g] = 0.f;
    }
}

// ---------------- K4: tiefix + output fused.
__global__ void k_finish(const unsigned* __restrict__ counters,
                         const unsigned long long* __restrict__ sorted,
                         const unsigned* __restrict__ sslot,
                         const float4* __restrict__ psums,
                         float4* __restrict__ out, float* __restrict__ valid) {
    unsigned np = counters[1]; if (np > PEAK_CAP) np = PEAK_CAP;
    unsigned t = blockIdx.x * 1024u + threadIdx.x;
    if (t >= np) return;
    unsigned long long key = sorted[t];
    unsigned bits = (unsigned)(key >> 32);
    unsigned s = t;
    while (s > 0 && (unsigned)(sorted[s - 1] >> 32) == bits) s--;
    unsigned myidx = (unsigned)key;
    unsigned rank = 0, e = s;
    while (e < np) {
        unsigned long long k2 = sorted[e];
        if ((unsigned)(k2 >> 32) != bits) break;
        if ((unsigned)k2 < myidx) rank++;
        e++;
    }
    unsigned row = s + rank;
    if (row >= KPEAKS) return;
    unsigned idx = myidx;
    int z = idx >> 18, y = (idx >> 9) & 511, x = idx & 511;
    float4 ps = psums[sslot[t]];
    float val = __uint_as_float(bits);
    float xloc = ps.y / ps.x, yloc = ps.z / ps.x, zloc = ps.w / ps.x;
    float xr = ((float)x + xloc - (float)(WW - 1) * 0.5f) * 0.1f;
    float yr = ((float)y + yloc - (float)(HH - 1) * 0.5f) * 0.1f;
    float zr = ((float)z + zloc + 0.5f) * 0.02f - 2.0f;
    out[row] = make_float4(xr, yr, zr, val);
    valid[row] = 1.f;
}

extern "C" void kernel_launch(void* const* d_in, const int* in_sizes, int n_in,
                              void* d_out, int out_size, void* d_ws, size_t ws_size,
                              hipStream_t stream) {
    const float* vol = (const float*)d_in[0];
    // d_in[1] = max_peaks scalar (device); fixed at 131072 for this problem.

    char* w = (char*)d_ws;
    unsigned* counters = (unsigned*)w;                                   // 1 KB
    unsigned* hist     = (unsigned*)(w + 1024);                          // 256 KB
    unsigned* cursor   = (unsigned*)(w + 1024 + NBINS * 4);              // 256 KB
    char* w2 = w + 1024 + 2 * NBINS * 4;
    unsigned long long* keys   = (unsigned long long*)w2;                // 2 MB
    unsigned long long* sorted = keys + PEAK_CAP;                        // 2 MB
    unsigned* sslot = (unsigned*)(sorted + PEAK_CAP);                    // 1 MB
    float4*   psums = (float4*)(sslot + PEAK_CAP);                       // 4 MB
    unsigned* blocksum = (unsigned*)(psums + PEAK_CAP);                  // 1 KB
    // total ~9.5 MB of ws. blocksum is DEDICATED now: the fused k_scatter
    // reads it while writing sslot, so the old sslot-aliasing was a race.

    float* out_rows = (float*)d_out;                 // (131072, 4)
    float* valid = out_rows + (size_t)KPEAKS * 4;    // (131072,)

    k_init<<<NBINS / 1024, 1024, 0, stream>>>(counters, hist);
    k_find<<<NVOX / 16384, 512, 0, stream>>>((const float4*)vol, vol, counters, hist, keys, psums);
    k_scan_a<<<256, 256, 0, stream>>>(hist, cursor, blocksum);
    k_scatter<<<PEAK_CAP / 1024, 1024, 0, stream>>>(counters, keys, blocksum, cursor,
                                                    sorted, sslot,
                                                    (float4*)out_rows, valid);
    k_finish<<<PEAK_CAP / 1024, 1024, 0, stream>>>(counters, sorted, sslot, psums,
                                                   (float4*)out_rows, valid);
}

// Round 10
// 241.890 us; speedup vs baseline: 1.0444x; 1.0444x over previous
//
#include <hip/hip_runtime.h>

#define DD 128
#define HH 512
#define WW 512
#define NVOX (DD*HH*WW)          // 33554432
#define THRESHV 0.997f
#define KPEAKS 131072
#define PEAK_CAP (1u<<18)        // 262144 peak slots (expect ~63K)
#define NBINS 65536

// peaks all lie in (0.997, 1.0): float bits have constant upper 16 bits
// 0x3F7F -> low 16 bits monotone in value. bin=(~bits)&0xFFFF so ascending
// bin == descending value. Exact-value ties are COMMON -> tie-fix required.

// ---------------- K0: init scratch (ws is poisoned 0xAA before every call).
__global__ void k_init(unsigned* counters, unsigned* hist) {
    unsigned t = blockIdx.x * 1024u + threadIdx.x;
    if (t < 64) counters[t] = 0u;
    if (t < NBINS) hist[t] = 0u;
}

// ---------------- K1: FUSED scan + verify + centroid. 512 thr x 4096 blk.
// R18: R0's geometry and verify, with the scan's LDS round-trip removed.
// Model (R15+R17 evidence): scan(50us) + verify(34us) are ADDITIVE -- both
// contend for the per-CU memory pipe; L3-resident replays run at identical
// speed (structure-bound, not BW-bound). So the only lever is cheaper
// memory ops. global_load_lds convoy measured ~4.4 B/cyc/CU; plain float4
// register loads reach ~10 B/cyc/CU (m13). Geometry is preserved WITHOUT
// an LDS tile: 512-thr blocks hit the 32-wave/CU cap at exactly 4
// blocks/CU -> concurrent slab footprint 4x32KB x 32CU = 4MB/XCD = L2
// budget (R16's FETCH blowup came from 256-thr blocks reaching 8/CU).
// 4 NAMED loads + sched_barrier(0) = parallel issue (R16: compiles at
// VGPR~28-40 with all 4 in flight).
__global__ __launch_bounds__(512, 8)
void k_find(const float4* __restrict__ vol4, const float* __restrict__ vol,
            unsigned* counters, unsigned* hist,
            unsigned long long* keys, float4* psums) {
    __shared__ unsigned lcnt, pcnt, lbase;
    __shared__ unsigned cidx[384];            // candidate voxel indices (E~25)
    __shared__ unsigned long long lbuf[192];  // surviving peak keys (E~16)
    __shared__ float4 sbuf[192];              // surviving peak centroid sums
    if (threadIdx.x == 0) { lcnt = 0; pcnt = 0; }
    __syncthreads();

    unsigned t = threadIdx.x;
    unsigned lane = t & 63u;
    unsigned w = t >> 6;                      // wave id 0..7 (wave-uniform)
    unsigned blockBase4 = blockIdx.x * 2048u; // float4 units; 8192 voxels

    // ---- threshold scan: 4 independent named float4 loads straight to
    // registers (16 data VGPRs live at the fence -> 4-deep MLP/wave).
    unsigned b4 = blockBase4 + t;
    float4 a0 = vol4[b4];
    float4 a1 = vol4[b4 + 512u];
    float4 a2 = vol4[b4 + 1024u];
    float4 a3 = vol4[b4 + 1536u];
    __builtin_amdgcn_sched_barrier(0);        // no use hoisted above loads
    unsigned m = 0u;
    m |= (a0.x > THRESHV ? 1u : 0u);
    m |= (a0.y > THRESHV ? 2u : 0u);
    m |= (a0.z > THRESHV ? 4u : 0u);
    m |= (a0.w > THRESHV ? 8u : 0u);
    m |= (a1.x > THRESHV ? 16u : 0u);
    m |= (a1.y > THRESHV ? 32u : 0u);
    m |= (a1.z > THRESHV ? 64u : 0u);
    m |= (a1.w > THRESHV ? 128u : 0u);
    m |= (a2.x > THRESHV ? 256u : 0u);
    m |= (a2.y > THRESHV ? 512u : 0u);
    m |= (a2.z > THRESHV ? 1024u : 0u);
    m |= (a2.w > THRESHV ? 2048u : 0u);
    m |= (a3.x > THRESHV ? 4096u : 0u);
    m |= (a3.y > THRESHV ? 8192u : 0u);
    m |= (a3.z > THRESHV ? 16384u : 0u);
    m |= (a3.w > THRESHV ? 32768u : 0u);
    while (m) {
        int b = __ffs(m) - 1;
        m &= m - 1u;
        unsigned f4 = blockBase4 + (unsigned)(b >> 2) * 512u + t;
        cidx[atomicAdd(&lcnt, 1u) & 383u] = f4 * 4u + (unsigned)(b & 3);
    }
    __syncthreads();

    // ---- Phase B: verify, 2 candidates per wave iteration (8 waves),
    // R0-verbatim. Slab lines are L2-warm from the register pass above.
    unsigned n = lcnt > 384u ? 384u : lcnt;
    int dz = (int)lane / 7, dy = (int)lane - dz * 7;   // meaningful for lane<49
    for (unsigned base = w * 2u; base < n; base += 16u) {
        bool has2 = (base + 1u < n);
        unsigned idxA = cidx[base];
        unsigned idxB = has2 ? cidx[base + 1u] : idxA;
        int zA = idxA >> 18, yA = (idxA >> 9) & 511, xA = idxA & 511;
        int zB = idxB >> 18, yB = (idxB >> 9) & 511, xB = idxB & 511;
        int nzA = zA + dz - 3, nyA = yA + dy - 3;
        int nzB = zB + dz - 3, nyB = yB + dy - 3;
        bool rowokA = (lane < 49) && ((unsigned)nzA < DD) && ((unsigned)nyA < HH);
        bool rowokB = (lane < 49) && ((unsigned)nzB < DD) && ((unsigned)nyB < HH);
        size_t rbA = rowokA ? (((size_t)(unsigned)nzA << 18) | ((size_t)(unsigned)nyA << 9))
                            : (((size_t)zA << 18) | ((size_t)yA << 9));
        size_t rbB = rowokB ? (((size_t)(unsigned)nzB << 18) | ((size_t)(unsigned)nyB << 9))
                            : (((size_t)zB << 18) | ((size_t)yB << 9));
        float rvA[7], rvB[7];
        bool intAB = (xA >= 3) && (xA <= WW - 4) && (xB >= 3) && (xB <= WW - 4);
        if (intAB) {
            float4 fA0 = *(const float4*)(vol + rbA + (unsigned)(xA - 3));
            float4 fA1 = *(const float4*)(vol + rbA + (unsigned)(xA + 1));
            float4 fB0 = *(const float4*)(vol + rbB + (unsigned)(xB - 3));
            float4 fB1 = *(const float4*)(vol + rbB + (unsigned)(xB + 1));
            rvA[0] = fA0.x; rvA[1] = fA0.y; rvA[2] = fA0.z; rvA[3] = fA0.w;
            rvA[4] = fA1.x; rvA[5] = fA1.y; rvA[6] = fA1.z;
            rvB[0] = fB0.x; rvB[1] = fB0.y; rvB[2] = fB0.z; rvB[3] = fB0.w;
            rvB[4] = fB1.x; rvB[5] = fB1.y; rvB[6] = fB1.z;
        } else {
            // rare x-edge path (wave-uniform): clamped scalar loads
#pragma unroll
            for (int d = 0; d < 7; d++) {
                int nxA = xA + d - 3;
                bool okA = (unsigned)nxA < WW;
                float va = vol[rbA + (unsigned)(okA ? nxA : xA)];
                rvA[d] = okA ? va : 0.f;
                int nxB = xB + d - 3;
                bool okB = (unsigned)nxB < WW;
                float vb = vol[rbB + (unsigned)(okB ? nxB : xB)];
                rvB[d] = okB ? vb : 0.f;
            }
        }
        if (!rowokA) {
#pragma unroll
            for (int d = 0; d < 7; d++) rvA[d] = 0.f;
        }
        if (!rowokB) {
#pragma unroll
            for (int d = 0; d < 7; d++) rvB[d] = 0.f;
        }
        float centerA = __shfl(rvA[3], 24);
        float centerB = __shfl(rvB[3], 24);

        // ---- candidate A
        {
            bool kill = false;
            float s0r = 0.f, sxr = 0.f;
#pragma unroll
            for (int d = 0; d < 7; d++) {
                kill |= rvA[d] > centerA;
                s0r += rvA[d];
                sxr += rvA[d] * (float)(d - 3);
            }
            if (!__any(kill)) {
                float s0 = s0r, sx = sxr;
                float sy = s0r * (float)(dy - 3);
                float sz = s0r * (float)(dz - 3);
                for (int off = 32; off; off >>= 1) {
                    s0 += __shfl_down(s0, off);
                    sx += __shfl_down(sx, off);
                    sy += __shfl_down(sy, off);
                    sz += __shfl_down(sz, off);
                }
                if (lane == 0) {
                    unsigned bits = __float_as_uint(centerA);
                    atomicAdd(&hist[(~bits) & 0xFFFFu], 1u);
                    unsigned li = atomicAdd(&pcnt, 1u);
                    if (li < 192u) {
                        lbuf[li] = ((unsigned long long)bits << 32) | idxA;
                        sbuf[li] = make_float4(s0, sx, sy, sz);
                    }
                }
            }
        }
        // ---- candidate B
        if (has2) {
            bool kill = false;
            float s0r = 0.f, sxr = 0.f;
#pragma unroll
            for (int d = 0; d < 7; d++) {
                kill |= rvB[d] > centerB;
                s0r += rvB[d];
                sxr += rvB[d] * (float)(d - 3);
            }
            if (!__any(kill)) {
                float s0 = s0r, sx = sxr;
                float sy = s0r * (float)(dy - 3);
                float sz = s0r * (float)(dz - 3);
                for (int off = 32; off; off >>= 1) {
                    s0 += __shfl_down(s0, off);
                    sx += __shfl_down(sx, off);
                    sy += __shfl_down(sy, off);
                    sz += __shfl_down(sz, off);
                }
                if (lane == 0) {
                    unsigned bits = __float_as_uint(centerB);
                    atomicAdd(&hist[(~bits) & 0xFFFFu], 1u);
                    unsigned li = atomicAdd(&pcnt, 1u);
                    if (li < 192u) {
                        lbuf[li] = ((unsigned long long)bits << 32) | idxB;
                        sbuf[li] = make_float4(s0, sx, sy, sz);
                    }
                }
            }
        }
    }
    __syncthreads();
    if (threadIdx.x == 0) lbase = atomicAdd(&counters[1], pcnt);
    __syncthreads();
    unsigned np = pcnt > 192u ? 192u : pcnt;
    for (unsigned i = threadIdx.x; i < np; i += 512u) {
        unsigned p = lbase + i;
        if (p < PEAK_CAP) { keys[p] = lbuf[i]; psums[p] = sbuf[i]; }
    }
}

// ---------------- K2: parallel scan, stage 1. 256 blocks x 256 thr.
// Each block scans its 256-bin chunk; cursor gets the block-LOCAL exclusive
// prefix; blocksum gets the chunk total. Stage 2 is fused into k_scatter.
__global__ void k_scan_a(const unsigned* __restrict__ hist,
                         unsigned* __restrict__ cursor,
                         unsigned* __restrict__ blocksum) {
    __shared__ unsigned sc[256];
    unsigned t = threadIdx.x, b = blockIdx.x;
    unsigned h = hist[b * 256u + t];
    sc[t] = h;
    __syncthreads();
    for (unsigned off = 1u; off < 256u; off <<= 1) {
        unsigned v = (t >= off) ? sc[t - off] : 0u;
        __syncthreads();
        sc[t] += v;
        __syncthreads();
    }
    cursor[b * 256u + t] = sc[t] - h;         // block-local exclusive
    if (t == 255u) blocksum[b] = sc[255];
}

// ---------------- K3: scatter (with scan stage-2 fused). Each block first
// scans the 256 chunk totals in LDS (1KB, L2-hot), then final position =
// chunk_base[bin>>8] + atomicAdd(cursor[bin]) where cursor holds the
// block-local prefix -- algebraically identical to the old scan_b+scatter.
__global__ void k_scatter(const unsigned* __restrict__ counters,
                          const unsigned long long* __restrict__ keys,
                          const unsigned* __restrict__ blocksum,
                          unsigned* cursor, unsigned long long* sorted,
                          unsigned* sslot,
                          float4* __restrict__ out, float* __restrict__ valid) {
    __shared__ unsigned bs[256];
    unsigned t = threadIdx.x;
    if (t < 256u) bs[t] = blocksum[t];
    __syncthreads();
    for (unsigned off = 1u; off < 256u; off <<= 1) {
        unsigned v = (t < 256u && t >= off) ? bs[t - off] : 0u;
        __syncthreads();
        if (t < 256u) bs[t] += v;
        __syncthreads();
    }
    unsigned np = counters[1]; if (np > PEAK_CAP) np = PEAK_CAP;
    unsigned g = blockIdx.x * 1024u + t;
    if (g < np) {
        unsigned long long key = keys[g];
        unsigned bits = (unsigned)(key >> 32);
        unsigned bin = (~bits) & 0xFFFFu;
        unsigned c = bin >> 8;
        unsigned base_c = (c > 0u) ? bs[c - 1u] : 0u;
        unsigned pos = base_c + atomicAdd(&cursor[bin], 1u);
        if (pos < PEAK_CAP) { sorted[pos] = key; sslot[pos] = g; }
    } else if (g < KPEAKS) {
        out[g] = make_float4(0.f, 0.f, 0.f, 0.f);
        valid[g] = 0.f;
    }
}

// ---------------- K4: tiefix + output fused.
__global__ void k_finish(const unsigned* __restrict__ counters,
                         const unsigned long long* __restrict__ sorted,
                         const unsigned* __restrict__ sslot,
                         const float4* __restrict__ psums,
                         float4* __restrict__ out, float* __restrict__ valid) {
    unsigned np = counters[1]; if (np > PEAK_CAP) np = PEAK_CAP;
    unsigned t = blockIdx.x * 1024u + threadIdx.x;
    if (t >= np) return;
    unsigned long long key = sorted[t];
    unsigned bits = (unsigned)(key >> 32);
    unsigned s = t;
    while (s > 0 && (unsigned)(sorted[s - 1] >> 32) == bits) s--;
    unsigned myidx = (unsigned)key;
    unsigned rank = 0, e = s;
    while (e < np) {
        unsigned long long k2 = sorted[e];
        if ((unsigned)(k2 >> 32) != bits) break;
        if ((unsigned)k2 < myidx) rank++;
        e++;
    }
    unsigned row = s + rank;
    if (row >= KPEAKS) return;
    unsigned idx = myidx;
    int z = idx >> 18, y = (idx >> 9) & 511, x = idx & 511;
    float4 ps = psums[sslot[t]];
    float val = __uint_as_float(bits);
    float xloc = ps.y / ps.x, yloc = ps.z / ps.x, zloc = ps.w / ps.x;
    float xr = ((float)x + xloc - (float)(WW - 1) * 0.5f) * 0.1f;
    float yr = ((float)y + yloc - (float)(HH - 1) * 0.5f) * 0.1f;
    float zr = ((float)z + zloc + 0.5f) * 0.02f - 2.0f;
    out[row] = make_float4(xr, yr, zr, val);
    valid[row] = 1.f;
}

extern "C" void kernel_launch(void* const* d_in, const int* in_sizes, int n_in,
                              void* d_out, int out_size, void* d_ws, size_t ws_size,
                              hipStream_t stream) {
    const float* vol = (const float*)d_in[0];
    // d_in[1] = max_peaks scalar (device); fixed at 131072 for this problem.

    char* w = (char*)d_ws;
    unsigned* counters = (unsigned*)w;                                   // 1 KB
    unsigned* hist     = (unsigned*)(w + 1024);                          // 256 KB
    unsigned* cursor   = (unsigned*)(w + 1024 + NBINS * 4);              // 256 KB
    char* w2 = w + 1024 + 2 * NBINS * 4;
    unsigned long long* keys   = (unsigned long long*)w2;                // 2 MB
    unsigned long long* sorted = keys + PEAK_CAP;                        // 2 MB
    unsigned* sslot = (unsigned*)(sorted + PEAK_CAP);                    // 1 MB
    float4*   psums = (float4*)(sslot + PEAK_CAP);                       // 4 MB
    unsigned* blocksum = (unsigned*)(psums + PEAK_CAP);                  // 1 KB
    // total ~9.5 MB of ws. blocksum dedicated (fused k_scatter reads it
    // while writing sslot -- aliasing them would be a race).

    float* out_rows = (float*)d_out;                 // (131072, 4)
    float* valid = out_rows + (size_t)KPEAKS * 4;    // (131072,)

    k_init<<<NBINS / 1024, 1024, 0, stream>>>(counters, hist);
    k_find<<<NVOX / 8192, 512, 0, stream>>>((const float4*)vol, vol, counters, hist, keys, psums);
    k_scan_a<<<256, 256, 0, stream>>>(hist, cursor, blocksum);
    k_scatter<<<PEAK_CAP / 1024, 1024, 0, stream>>>(counters, keys, blocksum, cursor,
                                                    sorted, sslot,
                                                    (float4*)out_rows, valid);
    k_finish<<<PEAK_CAP / 1024, 1024, 0, stream>>>(counters, sorted, sslot, psums,
                                                   (float4*)out_rows, valid);
}